// Round 2
// baseline (59.998 us; speedup 1.0000x reference)
//
#include <hip/hip_runtime.h>
#include <math.h>

#define N_SPK 1024
#define M_UTT 32
#define M_ENR 16
#define M_TEST 16
#define D 512
#define N_TEST_ROWS (N_SPK * M_TEST)   // 16384

#define BM 128
#define BN 128
#define BK 64

typedef __attribute__((ext_vector_type(4))) float f32x4;
typedef __attribute__((ext_vector_type(8))) short short8;
typedef __attribute__((ext_vector_type(8))) unsigned short ushort8;

typedef const __attribute__((address_space(1))) void g_void;
typedef __attribute__((address_space(3))) void lds_void;

__device__ __forceinline__ unsigned short f2bf(float f) {
    unsigned int u = __float_as_uint(f);
    u += 0x7FFF + ((u >> 16) & 1);   // round-to-nearest-even
    return (unsigned short)(u >> 16);
}

// ---------------------------------------------------------------------------
// Kernel 1: centroids (mean of enroll half, L2-normalize) + test-row normalize.
// ---------------------------------------------------------------------------
__global__ __launch_bounds__(256) void prep_kernel(const float* __restrict__ emb,
                                                   unsigned short* __restrict__ cent,
                                                   unsigned short* __restrict__ test) {
    const int b = blockIdx.x;
    const int tid = threadIdx.x;
    const int lane = tid & 63;
    const int wid = tid >> 6;

    if (b < N_SPK) {
        const float* base = emb + (size_t)b * M_UTT * D;
        float a0 = 0.f, a1 = 0.f;
#pragma unroll
        for (int u = 0; u < M_ENR; ++u) {
            a0 += base[u * D + tid];
            a1 += base[u * D + tid + 256];
        }
        a0 *= (1.f / 16.f);
        a1 *= (1.f / 16.f);
        float ss = a0 * a0 + a1 * a1;
#pragma unroll
        for (int m = 1; m < 64; m <<= 1) ss += __shfl_xor(ss, m, 64);
        __shared__ float wss[4];
        if (lane == 0) wss[wid] = ss;
        __syncthreads();
        const float tot = wss[0] + wss[1] + wss[2] + wss[3];
        const float inv = 1.f / fmaxf(sqrtf(tot), 1e-8f);
        cent[b * D + tid] = f2bf(a0 * inv);
        cent[b * D + tid + 256] = f2bf(a1 * inv);
    } else {
        const int r = (b - N_SPK) * 4 + wid;   // test row 0..16383
        const int s = r >> 4, t = r & 15;
        const float* row = emb + ((size_t)s * M_UTT + M_ENR + t) * D;
        const f32x4* rv = (const f32x4*)row;
        const f32x4 v0 = rv[lane * 2];
        const f32x4 v1 = rv[lane * 2 + 1];
        float ss = v0[0]*v0[0] + v0[1]*v0[1] + v0[2]*v0[2] + v0[3]*v0[3]
                 + v1[0]*v1[0] + v1[1]*v1[1] + v1[2]*v1[2] + v1[3]*v1[3];
#pragma unroll
        for (int m = 1; m < 64; m <<= 1) ss += __shfl_xor(ss, m, 64);
        const float inv = 1.f / fmaxf(sqrtf(ss), 1e-8f);
        ushort8 o;
        o[0] = f2bf(v0[0] * inv); o[1] = f2bf(v0[1] * inv);
        o[2] = f2bf(v0[2] * inv); o[3] = f2bf(v0[3] * inv);
        o[4] = f2bf(v1[0] * inv); o[5] = f2bf(v1[1] * inv);
        o[6] = f2bf(v1[2] * inv); o[7] = f2bf(v1[3] * inv);
        *(ushort8*)&test[(size_t)r * D + lane * 8] = o;
    }
}

// ---------------------------------------------------------------------------
// Kernel 2: m97-structure GEMM. global_load_lds width=16, linear LDS [128][64],
// 2 barriers per K-step, 4 waves (2x2), 16x16x32 bf16 MFMA.
// Epilogue: e = exp(alpha*s+beta), fused per-row total + diagonal sums.
// ---------------------------------------------------------------------------
__global__ __launch_bounds__(256) void gemm_kernel(const unsigned short* __restrict__ A,  // cent 1024x512
                                                   const unsigned short* __restrict__ B,  // test 16384x512
                                                   const float* __restrict__ alpha_p,
                                                   const float* __restrict__ beta_p,
                                                   float* __restrict__ g_row,
                                                   float* __restrict__ g_pos) {
    __shared__ __align__(16) unsigned short As[BM * BK];
    __shared__ __align__(16) unsigned short Bs[BN * BK];
    __shared__ float rowsum[BM];
    __shared__ float possum[BM];

    const int tid = threadIdx.x;
    const int lane = tid & 63;
    const int w = tid >> 6;
    const int wr = w >> 1, wc = w & 1;

    // XCD-aware bijective swizzle: nwg = 1024 = 8 XCDs x 128 contiguous ids.
    // Each XCD then owns 16 consecutive bj panels (2 MB of B -> fits 4 MB L2, 8x reuse).
    const int raw = blockIdx.x;
    const int wg = (raw & 7) * 128 + (raw >> 3);
    const int bi = wg & 7;     // 8 row-blocks  (M = 1024)
    const int bj = wg >> 3;    // 128 col-blocks (N = 16384)
    const int row0 = bi * BM, col0 = bj * BN;
    const bool has_diag = ((bj >> 4) == bi);   // positive-pair cols live here only

    const float alpha = *alpha_p;
    const float beta = *beta_p;

    if (tid < BM) { rowsum[tid] = 0.f; possum[tid] = 0.f; }

    f32x4 acc[4][4] = {};

    for (int ks = 0; ks < 8; ++ks) {
        const int k0 = ks * BK;
        __syncthreads();   // prior tile's compute done (iter 0: rowsum init visible)
#pragma unroll
        for (int i = 0; i < 4; ++i) {
            const int c = i * 256 + tid;          // 16B chunk id 0..1023
            const int r = c >> 3, k8 = (c & 7) * 8;
            __builtin_amdgcn_global_load_lds(
                (g_void*)&A[(size_t)(row0 + r) * D + k0 + k8],
                (lds_void*)&As[(i * 256 + w * 64) * 8],   // wave-uniform base; lane*16B implicit
                16, 0, 0);
        }
#pragma unroll
        for (int i = 0; i < 4; ++i) {
            const int c = i * 256 + tid;
            const int r = c >> 3, k8 = (c & 7) * 8;
            __builtin_amdgcn_global_load_lds(
                (g_void*)&B[(size_t)(col0 + r) * D + k0 + k8],
                (lds_void*)&Bs[(i * 256 + w * 64) * 8],
                16, 0, 0);
        }
        __syncthreads();   // compiler drains vmcnt(0) before barrier -> LDS ready
#pragma unroll
        for (int kk = 0; kk < BK; kk += 32) {
            short8 af[4], bf[4];
#pragma unroll
            for (int mi = 0; mi < 4; ++mi)
                af[mi] = *(const short8*)&As[(wr * 64 + mi * 16 + (lane & 15)) * BK + kk + (lane >> 4) * 8];
#pragma unroll
            for (int ni = 0; ni < 4; ++ni)
                bf[ni] = *(const short8*)&Bs[(wc * 64 + ni * 16 + (lane & 15)) * BK + kk + (lane >> 4) * 8];
#pragma unroll
            for (int mi = 0; mi < 4; ++mi)
#pragma unroll
                for (int ni = 0; ni < 4; ++ni)
                    acc[mi][ni] = __builtin_amdgcn_mfma_f32_16x16x32_bf16(af[mi], bf[ni], acc[mi][ni], 0, 0, 0);
        }
    }

    // Epilogue: e = exp(alpha*s + beta); per-row sums over this block's 128 cols.
    // C/D layout (16x16x32): col = lane&15, row = (lane>>4)*4 + reg   [m89]
#pragma unroll
    for (int mi = 0; mi < 4; ++mi) {
#pragma unroll
        for (int r = 0; r < 4; ++r) {
            const int lrow = wr * 64 + mi * 16 + ((lane >> 4) << 2) + r;
            const int grow = row0 + lrow;
            float tot = 0.f, pos = 0.f;
#pragma unroll
            for (int ni = 0; ni < 4; ++ni) {
                const int gcol = col0 + wc * 64 + ni * 16 + (lane & 15);
                const float e = __expf(fmaf(alpha, acc[mi][ni][r], beta));
                tot += e;
                if (has_diag) pos += ((gcol >> 4) == grow) ? e : 0.f;
            }
#pragma unroll
            for (int m = 1; m < 16; m <<= 1) tot += __shfl_xor(tot, m, 64);
            if (has_diag) {
#pragma unroll
                for (int m = 1; m < 16; m <<= 1) pos += __shfl_xor(pos, m, 64);
            }
            if ((lane & 15) == 0) {
                atomicAdd(&rowsum[lrow], tot);
                if (has_diag) atomicAdd(&possum[lrow], pos);
            }
        }
    }
    __syncthreads();
    if (tid < BM) {
        atomicAdd(&g_row[row0 + tid], rowsum[tid]);
        if (has_diag) atomicAdd(&g_pos[row0 + tid], possum[tid]);
    }
}

// ---------------------------------------------------------------------------
// Kernel 3: loss = mean(log(tot - pos) - log(pos))
// ---------------------------------------------------------------------------
__global__ __launch_bounds__(1024) void finalize_kernel(const float* __restrict__ g_row,
                                                        const float* __restrict__ g_pos,
                                                        float* __restrict__ out) {
    __shared__ float red[1024];
    const int i = threadIdx.x;
    const float pos = g_pos[i];
    const float neg = g_row[i] - pos;
    red[i] = logf(fmaxf(neg, 1e-30f)) - logf(fmaxf(pos, 1e-30f));
    __syncthreads();
    for (int s = 512; s > 0; s >>= 1) {
        if (i < s) red[i] += red[i + s];
        __syncthreads();
    }
    if (i == 0) out[0] = red[0] * (1.f / 1024.f);
}

extern "C" void kernel_launch(void* const* d_in, const int* in_sizes, int n_in,
                              void* d_out, int out_size, void* d_ws, size_t ws_size,
                              hipStream_t stream) {
    const float* emb = (const float*)d_in[0];
    // d_in[1] = labels (unused; structure fixed by construction)
    const float* alpha_p = (const float*)d_in[2];
    const float* beta_p = (const float*)d_in[3];

    unsigned short* cent = (unsigned short*)d_ws;          // 1024*512 bf16 = 1 MB
    unsigned short* test = cent + (size_t)N_SPK * D;       // 16384*512 bf16 = 16 MB
    float* g_row = (float*)(test + (size_t)N_TEST_ROWS * D);
    float* g_pos = g_row + N_SPK;

    hipMemsetAsync(g_row, 0, 2 * N_SPK * sizeof(float), stream);

    prep_kernel<<<N_SPK + N_TEST_ROWS / 4, 256, 0, stream>>>(emb, cent, test);

    gemm_kernel<<<(N_SPK / BM) * (N_TEST_ROWS / BN), 256, 0, stream>>>(
        cent, test, alpha_p, beta_p, g_row, g_pos);

    finalize_kernel<<<1, 1024, 0, stream>>>(g_row, g_pos, (float*)d_out);
}

// Round 3
// 49.094 us; speedup vs baseline: 1.2221x; 1.2221x over previous
//
#include <hip/hip_runtime.h>
#include <math.h>

#define N_SPK 1024
#define M_UTT 32
#define M_ENR 16
#define M_TEST 16
#define D 512
#define N_TEST_ROWS (N_SPK * M_TEST)   // 16384

// gemm geometry: block = 512 thr (8 waves), tile 128M x 512N, wave = 128M x 64N
// grid = (1024/128) x (16384/512) = 8 x 32 = 256 blocks = 1 per CU.

typedef __attribute__((ext_vector_type(4))) float f32x4;
typedef __attribute__((ext_vector_type(8))) short short8;
typedef __attribute__((ext_vector_type(8))) unsigned short ushort8;

typedef const __attribute__((address_space(1))) void g_void;
typedef __attribute__((address_space(3))) void lds_void;

__device__ __forceinline__ unsigned short f2bf(float f) {
    unsigned int u = __float_as_uint(f);
    u += 0x7FFF + ((u >> 16) & 1);   // round-to-nearest-even
    return (unsigned short)(u >> 16);
}

// ---------------------------------------------------------------------------
// Kernel 1: centroids + test-row normalize; blocks [0,4) also zero g_row/g_pos.
// ---------------------------------------------------------------------------
__global__ __launch_bounds__(256) void prep_kernel(const float* __restrict__ emb,
                                                   unsigned short* __restrict__ cent,
                                                   unsigned short* __restrict__ test,
                                                   float* __restrict__ g_row,
                                                   float* __restrict__ g_pos) {
    const int b = blockIdx.x;
    const int tid = threadIdx.x;
    const int lane = tid & 63;
    const int wid = tid >> 6;

    if (b < 4) {   // zero the accumulators (replaces hipMemsetAsync dispatch)
        g_row[b * 256 + tid] = 0.f;
        g_pos[b * 256 + tid] = 0.f;
    }

    if (b < N_SPK) {
        const float* base = emb + (size_t)b * M_UTT * D;
        float a0 = 0.f, a1 = 0.f;
#pragma unroll
        for (int u = 0; u < M_ENR; ++u) {
            a0 += base[u * D + tid];
            a1 += base[u * D + tid + 256];
        }
        a0 *= (1.f / 16.f);
        a1 *= (1.f / 16.f);
        float ss = a0 * a0 + a1 * a1;
#pragma unroll
        for (int m = 1; m < 64; m <<= 1) ss += __shfl_xor(ss, m, 64);
        __shared__ float wss[4];
        if (lane == 0) wss[wid] = ss;
        __syncthreads();
        const float tot = wss[0] + wss[1] + wss[2] + wss[3];
        const float inv = 1.f / fmaxf(sqrtf(tot), 1e-8f);
        cent[b * D + tid] = f2bf(a0 * inv);
        cent[b * D + tid + 256] = f2bf(a1 * inv);
    } else {
        const int r = (b - N_SPK) * 4 + wid;   // test row 0..16383
        const int s = r >> 4, t = r & 15;
        const float* row = emb + ((size_t)s * M_UTT + M_ENR + t) * D;
        const f32x4* rv = (const f32x4*)row;
        const f32x4 v0 = rv[lane * 2];
        const f32x4 v1 = rv[lane * 2 + 1];
        float ss = v0[0]*v0[0] + v0[1]*v0[1] + v0[2]*v0[2] + v0[3]*v0[3]
                 + v1[0]*v1[0] + v1[1]*v1[1] + v1[2]*v1[2] + v1[3]*v1[3];
#pragma unroll
        for (int m = 1; m < 64; m <<= 1) ss += __shfl_xor(ss, m, 64);
        const float inv = 1.f / fmaxf(sqrtf(ss), 1e-8f);
        ushort8 o;
        o[0] = f2bf(v0[0] * inv); o[1] = f2bf(v0[1] * inv);
        o[2] = f2bf(v0[2] * inv); o[3] = f2bf(v0[3] * inv);
        o[4] = f2bf(v1[0] * inv); o[5] = f2bf(v1[1] * inv);
        o[6] = f2bf(v1[2] * inv); o[7] = f2bf(v1[3] * inv);
        *(ushort8*)&test[(size_t)r * D + lane * 8] = o;
    }
}

// ---------------------------------------------------------------------------
// Kernel 2: barrier-free K-loop GEMM for tiny-K / L2-resident-B regime.
//   - Full A panel [128][512] staged once in LDS via global_load_lds,
//     XOR-swizzled (pre-swizzled per-lane global source, linear LDS dest).
//   - B streamed from L2 straight to registers, 1-step prefetch, NO barriers
//     in the K-loop (kills the stage->drain->compute serialization).
//   - Epilogue: e = exp(alpha*s+beta), fused row totals + diagonal sums.
// ---------------------------------------------------------------------------
__global__ __launch_bounds__(512, 2) void gemm_kernel(const unsigned short* __restrict__ A,  // cent 1024x512
                                                      const unsigned short* __restrict__ B,  // test 16384x512
                                                      const float* __restrict__ alpha_p,
                                                      const float* __restrict__ beta_p,
                                                      float* __restrict__ g_row,
                                                      float* __restrict__ g_pos) {
    __shared__ __align__(16) unsigned short As[128 * 512];   // 128 KB, swizzled content
    __shared__ float rowsum[128];
    __shared__ float possum[128];

    const int tid = threadIdx.x;
    const int lane = tid & 63;
    const int w = tid >> 6;          // wave 0..7, owns cols [w*64, w*64+64)

    // XCD swizzle: 256 blocks = 8 XCDs x 32. Each XCD owns 4 consecutive bj
    // panels (2 MB of B) + A (1 MB) -> L2-resident.
    const int raw = blockIdx.x;
    const int wg = (raw & 7) * 32 + (raw >> 3);
    const int bi = wg & 7;           // 8 M-panels
    const int bj = wg >> 3;          // 32 N-panels
    const int row0 = bi * 128, col0 = bj * 512;
    const bool has_diag = ((bj >> 2) == bi);

    // ---- stage A panel: one row (1024 B) per wave-instruction, 16 rounds.
    // LDS[r][e] = A[row0+r][ e ^ ((r&7)<<3) ]  (elem-granularity-8 XOR swizzle)
#pragma unroll
    for (int it = 0; it < 16; ++it) {
        const int r = it * 8 + w;
        const int src = (row0 + r) * D + ((lane * 8) ^ ((r & 7) << 3));
        __builtin_amdgcn_global_load_lds((g_void*)&A[src],
                                         (lds_void*)&As[r * D],   // + lane*16B implicit
                                         16, 0, 0);
    }
    if (tid < 128) { rowsum[tid] = 0.f; possum[tid] = 0.f; }

    const float alpha = *alpha_p;
    const float beta = *beta_p;

    // per-lane B row pointers (col = bcol + ni*16 + (lane&15), k-offset (lane>>4)*8)
    const int bcol = col0 + w * 64;
    const unsigned short* bp[4];
#pragma unroll
    for (int ni = 0; ni < 4; ++ni)
        bp[ni] = &B[(size_t)(bcol + ni * 16 + (lane & 15)) * D + (lane >> 4) * 8];

    // swizzled LDS read offset component: (ko + (lane>>4)*8) ^ ((lane&7)<<3)
    //   = ko ^ hs   (no carries: disjoint/XOR-safe bit ranges)
    const int hs = ((lane >> 4) * 8) ^ ((lane & 7) << 3);
    const int arow_base = (lane & 15) * D;   // + mi*16*D per frag

    f32x4 acc[8][4] = {};
    short8 bf0[4], bf1[4];

#define LOADB(dst, kk)                                             \
    {                                                              \
        const int kp_ = (kk);                                      \
        _Pragma("unroll") for (int ni = 0; ni < 4; ++ni)           \
            dst[ni] = *(const short8*)(bp[ni] + kp_);              \
    }

#define STEP(bfr, kk)                                                          \
    {                                                                          \
        const int ofs_ = (kk) ^ hs;                                            \
        _Pragma("unroll") for (int mi = 0; mi < 8; ++mi) {                     \
            const short8 af_ = *(const short8*)&As[mi * 16 * D + arow_base + ofs_]; \
            _Pragma("unroll") for (int ni = 0; ni < 4; ++ni)                   \
                acc[mi][ni] = __builtin_amdgcn_mfma_f32_16x16x32_bf16(         \
                    af_, bfr[ni], acc[mi][ni], 0, 0, 0);                       \
        }                                                                      \
    }

    LOADB(bf0, 0);
    __syncthreads();   // A staged (drains vmcnt; bf0 also ready)

    for (int ko = 0; ko < D; ko += 64) {
        LOADB(bf1, ko + 32);
        STEP(bf0, ko);
        LOADB(bf0, (ko + 64) & (D - 1));   // last-iter wrap: harmless reload
        STEP(bf1, ko + 32);
    }

    // ---- epilogue: e = exp(alpha*s + beta); row totals + diagonal sums.
    // C/D layout (16x16x32): col = lane&15, row = (lane>>4)*4 + reg   [m89]
#pragma unroll
    for (int mi = 0; mi < 8; ++mi) {
#pragma unroll
        for (int r = 0; r < 4; ++r) {
            const int lrow = mi * 16 + ((lane >> 4) << 2) + r;
            const int grow = row0 + lrow;
            float tot = 0.f, pos = 0.f;
#pragma unroll
            for (int ni = 0; ni < 4; ++ni) {
                const int gcol = bcol + ni * 16 + (lane & 15);
                const float e = __expf(fmaf(alpha, acc[mi][ni][r], beta));
                tot += e;
                if (has_diag) pos += ((gcol >> 4) == grow) ? e : 0.f;
            }
#pragma unroll
            for (int m = 1; m < 16; m <<= 1) tot += __shfl_xor(tot, m, 64);
            if (has_diag) {
#pragma unroll
                for (int m = 1; m < 16; m <<= 1) pos += __shfl_xor(pos, m, 64);
            }
            if ((lane & 15) == 0) {
                atomicAdd(&rowsum[lrow], tot);
                if (has_diag) atomicAdd(&possum[lrow], pos);
            }
        }
    }
    __syncthreads();
    if (tid < 128) {
        atomicAdd(&g_row[row0 + tid], rowsum[tid]);
        if (has_diag) atomicAdd(&g_pos[row0 + tid], possum[tid]);
    }
#undef LOADB
#undef STEP
}

// ---------------------------------------------------------------------------
// Kernel 3: loss = mean(log(tot - pos) - log(pos))
// ---------------------------------------------------------------------------
__global__ __launch_bounds__(1024) void finalize_kernel(const float* __restrict__ g_row,
                                                        const float* __restrict__ g_pos,
                                                        float* __restrict__ out) {
    __shared__ float red[1024];
    const int i = threadIdx.x;
    const float pos = g_pos[i];
    const float neg = g_row[i] - pos;
    red[i] = logf(fmaxf(neg, 1e-30f)) - logf(fmaxf(pos, 1e-30f));
    __syncthreads();
    for (int s = 512; s > 0; s >>= 1) {
        if (i < s) red[i] += red[i + s];
        __syncthreads();
    }
    if (i == 0) out[0] = red[0] * (1.f / 1024.f);
}

extern "C" void kernel_launch(void* const* d_in, const int* in_sizes, int n_in,
                              void* d_out, int out_size, void* d_ws, size_t ws_size,
                              hipStream_t stream) {
    const float* emb = (const float*)d_in[0];
    // d_in[1] = labels (unused; structure fixed by construction)
    const float* alpha_p = (const float*)d_in[2];
    const float* beta_p = (const float*)d_in[3];

    unsigned short* cent = (unsigned short*)d_ws;          // 1024*512 bf16 = 1 MB
    unsigned short* test = cent + (size_t)N_SPK * D;       // 16384*512 bf16 = 16 MB
    float* g_row = (float*)(test + (size_t)N_TEST_ROWS * D);
    float* g_pos = g_row + N_SPK;

    prep_kernel<<<N_SPK + N_TEST_ROWS / 4, 256, 0, stream>>>(emb, cent, test, g_row, g_pos);

    gemm_kernel<<<256, 512, 0, stream>>>(cent, test, alpha_p, beta_p, g_row, g_pos);

    finalize_kernel<<<1, 1024, 0, stream>>>(g_row, g_pos, (float*)d_out);
}